// Round 7
// baseline (138.870 us; speedup 1.0000x reference)
//
#include <hip/hip_runtime.h>
#include <hip/hip_bf16.h>
#include <stdint.h>

// Problem constants
#define NS 32          // samples
#define NA 512         // atoms
#define IND 64         // in_depth
#define OD 64          // out_depth
#define FL 12          // filter_length
#define KTOT (NA*FL)   // 6144 contraction length (k = n*12 + f)
#define WROW 66        // filters innermost dim (in_depth+2)

typedef __bf16 bf16x8 __attribute__((ext_vector_type(8)));
typedef float  f32x4  __attribute__((ext_vector_type(4)));
typedef float  f32x4a __attribute__((ext_vector_type(4), aligned(4)));  // 4B-aligned vec load

// ---------------------------------------------------------------------------
// Fused kernel 1: blocks [0,512) = prep (MFMA Gt build), [512, 512+4096) =
// init (bond-term base for k_main's atomicAdd).
//
// prep: Gt[s][o][n*12+f] = sum_d node[s][n][d]*W[o][f][d]  (bf16)
//   Block = (s, n-quarter 128, o-group 16). 512 blocks -> 2/CU, 8 waves/CU.
//   - node quarter staged f32->bf16 in LDS [128][64] XOR-swizzled (verified
//     round 6), B-fragment ds_read_b128 conflict-free.
//   - A-fragments (W) preloaded once per wave (verified round 6).
//   - NO LDS transpose: D-accumulators stored directly, 3x uint2 (24 B) per
//     (o,n) — per o-row 16 lanes make a 384 B contiguous run (round-3 proven
//     pattern). Removes the serial per-tile transpose tail.
// ---------------------------------------------------------------------------
__global__ __launch_bounds__(256)
void k_prep_init(const float* __restrict__ node, const float* __restrict__ W,
                 const float* __restrict__ bond, __bf16* __restrict__ gt,
                 float* __restrict__ out) {
    __shared__ __align__(16) unsigned char SMEM[16640];
    const int bid = blockIdx.x;
    const int tid = threadIdx.x;

    if (bid < 512) {
        // ================= prep =================
        const int s  = bid >> 4;             // 0..31
        const int nq = (bid >> 2) & 3;       // 0..3 n-quarter
        const int og = bid & 3;              // 0..3
        const int o0 = og * 16;
        const int nbase = nq * 128;
        const int wv = tid >> 6, l = tid & 63;
        const int lr = l & 15, lg = l >> 4;
        unsigned char* NodeL = SMEM;         // [128 n][64 d] bf16, swizzled

        // ---- A-fragment preload (W rows; o=lane&15, k=8*(lane>>4)+j) ----
        bf16x8 afr[FL][2];
        {
            const float* wrow = W + (size_t)(o0 + lr) * (FL * WROW);
            #pragma unroll
            for (int f = 0; f < FL; ++f) {
                #pragma unroll
                for (int kk = 0; kk < 2; ++kk) {
                    const float* p = wrow + f * WROW + kk * 32 + lg * 8;
                    const f32x4a u0 = *reinterpret_cast<const f32x4a*>(p);
                    const f32x4a u1 = *reinterpret_cast<const f32x4a*>(p + 4);
                    bf16x8 a;
                    a[0] = (__bf16)u0.x; a[1] = (__bf16)u0.y;
                    a[2] = (__bf16)u0.z; a[3] = (__bf16)u0.w;
                    a[4] = (__bf16)u1.x; a[5] = (__bf16)u1.y;
                    a[6] = (__bf16)u1.z; a[7] = (__bf16)u1.w;
                    afr[f][kk] = a;
                }
            }
        }

        // ---- stage node[s][nbase..+128][0:64] -> bf16 LDS, swizzled ----
        {
            const f32x4* np = reinterpret_cast<const f32x4*>(
                node + ((size_t)s * NA + nbase) * IND);
            #pragma unroll
            for (int i = 0; i < 8; ++i) {
                const int idx = tid + 256 * i;      // f32x4 index 0..2047
                const f32x4 v = np[idx];
                const int n  = idx >> 4;
                const int c8 = idx & 15;
                union { __bf16 b[4]; uint2 u; } cv;
                cv.b[0] = (__bf16)v.x; cv.b[1] = (__bf16)v.y;
                cv.b[2] = (__bf16)v.z; cv.b[3] = (__bf16)v.w;
                const int woff = n * 128 + ((c8 * 8) ^ ((n & 7) << 4));
                *reinterpret_cast<uint2*>(NodeL + woff) = cv.u;
            }
        }
        __syncthreads();

        const int swk = (lr & 7) << 4;
        #pragma unroll
        for (int i = 0; i < 2; ++i) {               // 2 n-tiles per wave
            const int ln0 = (wv * 2 + i) * 16;      // multiple of 16
            const int nrow = ln0 + lr;
            f32x4 acc[FL];
            #pragma unroll
            for (int f = 0; f < FL; ++f) acc[f] = f32x4{0.f, 0.f, 0.f, 0.f};

            #pragma unroll
            for (int kk = 0; kk < 2; ++kk) {
                const int roff = nrow * 128 + (((kk * 4 + lg) * 16) ^ swk);
                const bf16x8 b = *reinterpret_cast<const bf16x8*>(NodeL + roff);
                #pragma unroll
                for (int f = 0; f < FL; ++f)
                    acc[f] = __builtin_amdgcn_mfma_f32_16x16x32_bf16(afr[f][kk], b, acc[f], 0, 0, 0);
            }

            // direct store: lane (r) -> o = o0+4*lg+r, n = nbase+ln0+lr
            #pragma unroll
            for (int r = 0; r < 4; ++r) {
                const int o = o0 + 4 * lg + r;
                const int n = nbase + ln0 + lr;
                union { __bf16 b[FL]; uint2 u[3]; } pk;
                #pragma unroll
                for (int f = 0; f < FL; ++f) pk.b[f] = (__bf16)acc[f][r];
                uint2* dst = reinterpret_cast<uint2*>(
                    gt + ((size_t)(s * OD + o)) * KTOT + (size_t)n * FL);
                dst[0] = pk.u[0]; dst[1] = pk.u[1]; dst[2] = pk.u[2];
            }
        }
    } else {
        // ================= init (bond-term base) =================
        const int ib = bid - 512;            // 0..4095, atoms [ib*4, ib*4+4)
        float* Wb = reinterpret_cast<float*>(SMEM);            // [64][25]
        float* bl = reinterpret_cast<float*>(SMEM + 6400);     // [4][24]
        for (int i = tid; i < 64 * 24; i += 256) {
            const int o = i / 24, fc = i % 24;
            const int f = fc >> 1, c = fc & 1;
            Wb[o * 25 + fc] = W[(size_t)o * (FL * WROW) + f * WROW + IND + c];
        }
        if (tid < 96) {
            const int a = tid / 24, fc = tid % 24;
            bl[a * 24 + fc] = bond[(size_t)ib * 4 * (FL * 2) + a * (FL * 2) + fc];
        }
        __syncthreads();

        const int aL = tid >> 6, o = tid & 63;
        float sum = 0.f;
        #pragma unroll
        for (int f = 0; f < FL; ++f)
            sum += bl[aL * 24 + 2 * f] * Wb[o * 25 + 2 * f]
                 + bl[aL * 24 + 2 * f + 1] * Wb[o * 25 + 2 * f + 1];
        out[((size_t)ib * 4 + aL) * OD + o] = sum;
    }
}

// ---------------------------------------------------------------------------
// Kernel 2 (validated ~86us, untouched): pipelined LDS-staged MFMA GEMM.
// One raw s_barrier per K-step, explicit lgkmcnt(0) (no vmcnt drain), 2-deep
// register prefetch -> counted vmcnt waits, loads in flight across barriers.
// ---------------------------------------------------------------------------
struct PF { f32x4 a0, a1, a2, a3; uint4 b0, b1; };

__device__ __forceinline__ PF pf_load(const float* ap, const __bf16* bp) {
    PF p;
    p.a0 = *reinterpret_cast<const f32x4*>(ap);
    p.a1 = *reinterpret_cast<const f32x4*>(ap + 4);
    p.a2 = *reinterpret_cast<const f32x4*>(ap + 8);
    p.a3 = *reinterpret_cast<const f32x4*>(ap + 12);
    p.b0 = *reinterpret_cast<const uint4*>(bp);
    p.b1 = *reinterpret_cast<const uint4*>(bp + 8);
    return p;
}

__device__ __forceinline__ void pf_stage(unsigned char* Ab, unsigned char* Bb,
                                         const PF& p, int woff0, int woff1) {
    bf16x8 wlo, whi;
    wlo[0] = (__bf16)p.a0.x; wlo[1] = (__bf16)p.a0.y;
    wlo[2] = (__bf16)p.a0.z; wlo[3] = (__bf16)p.a0.w;
    wlo[4] = (__bf16)p.a1.x; wlo[5] = (__bf16)p.a1.y;
    wlo[6] = (__bf16)p.a1.z; wlo[7] = (__bf16)p.a1.w;
    whi[0] = (__bf16)p.a2.x; whi[1] = (__bf16)p.a2.y;
    whi[2] = (__bf16)p.a2.z; whi[3] = (__bf16)p.a2.w;
    whi[4] = (__bf16)p.a3.x; whi[5] = (__bf16)p.a3.y;
    whi[6] = (__bf16)p.a3.z; whi[7] = (__bf16)p.a3.w;
    *reinterpret_cast<bf16x8*>(Ab + woff0) = wlo;
    *reinterpret_cast<bf16x8*>(Ab + woff1) = whi;
    *reinterpret_cast<uint4*>(Bb + woff0) = p.b0;
    *reinterpret_cast<uint4*>(Bb + woff1) = p.b1;
}

__device__ __forceinline__ void mfma_phase(const unsigned char* Ab, const unsigned char* Bb,
                                           int rowA0, int rowB0, int lg, int rsw,
                                           f32x4& c00, f32x4& c01, f32x4& c10, f32x4& c11) {
    #pragma unroll
    for (int ks = 0; ks < 2; ++ks) {
        const int koff = (ks * 64 + lg * 16) ^ rsw;
        const bf16x8 am0 = *reinterpret_cast<const bf16x8*>(Ab + rowA0 + koff);
        const bf16x8 am1 = *reinterpret_cast<const bf16x8*>(Ab + rowA0 + 2048 + koff);
        const bf16x8 bn0 = *reinterpret_cast<const bf16x8*>(Bb + rowB0 + koff);
        const bf16x8 bn1 = *reinterpret_cast<const bf16x8*>(Bb + rowB0 + 2048 + koff);
        c00 = __builtin_amdgcn_mfma_f32_16x16x32_bf16(am0, bn0, c00, 0, 0, 0);
        c01 = __builtin_amdgcn_mfma_f32_16x16x32_bf16(am0, bn1, c01, 0, 0, 0);
        c10 = __builtin_amdgcn_mfma_f32_16x16x32_bf16(am1, bn0, c10, 0, 0, 0);
        c11 = __builtin_amdgcn_mfma_f32_16x16x32_bf16(am1, bn1, c11, 0, 0, 0);
    }
}

__global__ __launch_bounds__(256, 4)
void k_main(const float* __restrict__ conn, const __bf16* __restrict__ gt,
            float* __restrict__ out) {
    const int bid = blockIdx.x;
    const int s  = bid & 31;
    const int x  = bid >> 5;
    const int at = x >> 2;            // 0..7
    const int kq = x & 3;             // 0..3
    const int a0 = at << 6;
    const int k00 = kq * (KTOT / 4);  // 1536-elem K slice, 24 steps of 64
    const int tid = threadIdx.x;
    const int w  = tid >> 6, l = tid & 63;
    const int lr = l & 15, lg = l >> 4;
    const int m0 = (w >> 1) << 5;
    const int n0 = (w & 1) << 5;

    __shared__ __align__(16) unsigned char Al0[8192];
    __shared__ __align__(16) unsigned char Al1[8192];
    __shared__ __align__(16) unsigned char Bl0[8192];
    __shared__ __align__(16) unsigned char Bl1[8192];

    const int srow = tid >> 2;
    const int scol = tid & 3;
    const float*  aG = conn + ((size_t)s * NA + a0 + srow) * KTOT + k00 + scol * 16;
    const __bf16* bG = gt   + ((size_t)s * OD + srow)      * KTOT + k00 + scol * 16;
    const int wsw   = (srow & 7) << 4;
    const int woff0 = srow * 128 + ((scol * 32) ^ wsw);
    const int woff1 = srow * 128 + ((scol * 32 + 16) ^ wsw);

    f32x4 acc00 = {0.f,0.f,0.f,0.f}, acc01 = {0.f,0.f,0.f,0.f};
    f32x4 acc10 = {0.f,0.f,0.f,0.f}, acc11 = {0.f,0.f,0.f,0.f};

    const int rsw = (lr & 7) << 4;
    const int rowA0 = (m0 + lr) * 128;
    const int rowB0 = (n0 + lr) * 128;

    PF P0 = pf_load(aG, bG);
    PF P1 = pf_load(aG + 64, bG + 64);

    #pragma unroll 1
    for (int t = 0; t < 24; t += 2) {
        // ---- even step: buffer 0 ----
        pf_stage(Al0, Bl0, P0, woff0, woff1);          // waits vmcnt(6): P1 in flight
        if (t + 2 < 24) P0 = pf_load(aG + (t + 2) * 64, bG + (t + 2) * 64);
        asm volatile("s_waitcnt lgkmcnt(0)" ::: "memory");
        __builtin_amdgcn_s_barrier();
        mfma_phase(Al0, Bl0, rowA0, rowB0, lg, rsw, acc00, acc01, acc10, acc11);

        // ---- odd step: buffer 1 ----
        pf_stage(Al1, Bl1, P1, woff0, woff1);
        if (t + 3 < 24) P1 = pf_load(aG + (t + 3) * 64, bG + (t + 3) * 64);
        asm volatile("s_waitcnt lgkmcnt(0)" ::: "memory");
        __builtin_amdgcn_s_barrier();
        mfma_phase(Al1, Bl1, rowA0, rowB0, lg, rsw, acc00, acc01, acc10, acc11);
    }

    // epilogue: atomic accumulate partials. D: col=lane&15, row=4*(lane>>4)+r
    float* ob = out + ((size_t)s * NA + a0 + m0 + lg * 4) * OD + n0 + lr;
    #pragma unroll
    for (int r = 0; r < 4; ++r) {
        atomicAdd(ob + (size_t)(r) * OD,            acc00[r]);
        atomicAdd(ob + (size_t)(r) * OD + 16,       acc01[r]);
        atomicAdd(ob + (size_t)(16 + r) * OD,       acc10[r]);
        atomicAdd(ob + (size_t)(16 + r) * OD + 16,  acc11[r]);
    }
}

extern "C" void kernel_launch(void* const* d_in, const int* in_sizes, int n_in,
                              void* d_out, int out_size, void* d_ws, size_t ws_size,
                              hipStream_t stream) {
    const float* node = (const float*)d_in[0];
    const float* conn = (const float*)d_in[1];
    const float* bond = (const float*)d_in[2];
    const float* W    = (const float*)d_in[3];
    float* out = (float*)d_out;
    __bf16* gt = (__bf16*)d_ws;    // 32*64*6144 bf16 = 25.2 MB

    k_prep_init<<<dim3(512 + NS * NA / 4), dim3(256), 0, stream>>>(node, W, bond, gt, out);
    k_main<<<dim3(NS * 32), dim3(256), 0, stream>>>(conn, gt, out);
}

// Round 8
// 128.107 us; speedup vs baseline: 1.0840x; 1.0840x over previous
//
#include <hip/hip_runtime.h>
#include <hip/hip_bf16.h>
#include <stdint.h>

// Problem constants
#define NS 32          // samples
#define NA 512         // atoms
#define IND 64         // in_depth
#define OD 64          // out_depth
#define FL 12          // filter_length
#define KTOT (NA*FL)   // 6144 contraction length (k = n*12 + f)
#define WROW 66        // filters innermost dim (in_depth+2)

typedef __bf16 bf16x8 __attribute__((ext_vector_type(8)));
typedef float  f32x4  __attribute__((ext_vector_type(4)));
typedef float  f32x4a __attribute__((ext_vector_type(4), aligned(4)));  // 4B-aligned vec load

// ---------------------------------------------------------------------------
// Kernel 1 (v5, MFMA, low-VGPR): Gt[s][o][n*12+f] = sum_d node[s][n][d]*W[o][f][d]
// Block = (s, n-chunk 64, o-group 16), grid 1024 -> 4+/CU. 4 waves, each ONE
// 16n x 16o tile. Key change vs round 6: A-fragments are TRANSIENT (loaded
// from W inside the f-loop, L1-hot) instead of 96 VGPRs held across the
// block -> VGPR ~90, 4-5 waves/SIMD, latency hidden by TLP.
// Math/layouts identical to validated round-6 prep.
// ---------------------------------------------------------------------------
__global__ __launch_bounds__(256)
void k_prep(const float* __restrict__ node, const float* __restrict__ W,
            __bf16* __restrict__ gt) {
    const int bid = blockIdx.x;          // 1024 blocks
    const int og = bid & 3;              // 0..3
    const int nq = (bid >> 2) & 7;       // 0..7
    const int s  = bid >> 5;             // 0..31
    const int o0 = og * 16;
    const int nbase = nq * 64;
    const int tid = threadIdx.x;
    const int wv = tid >> 6, l = tid & 63;
    const int lr = l & 15, lg = l >> 4;

    __shared__ __align__(16) unsigned char NodeL[64 * 128];   // [64 n][64 d] bf16, swizzled

    // ---- stage node[s][nbase..+64][0:64] -> bf16 LDS, swizzled, coalesced ----
    {
        const f32x4* np = reinterpret_cast<const f32x4*>(
            node + ((size_t)s * NA + nbase) * IND);
        #pragma unroll
        for (int i = 0; i < 4; ++i) {
            const int idx = tid + 256 * i;      // f32x4 index 0..1023
            const f32x4 v = np[idx];
            const int n  = idx >> 4;
            const int c8 = idx & 15;
            union { __bf16 b[4]; uint2 u; } cv;
            cv.b[0] = (__bf16)v.x; cv.b[1] = (__bf16)v.y;
            cv.b[2] = (__bf16)v.z; cv.b[3] = (__bf16)v.w;
            const int woff = n * 128 + ((c8 * 8) ^ ((n & 7) << 4));
            *reinterpret_cast<uint2*>(NodeL + woff) = cv.u;
        }
    }
    __syncthreads();

    // ---- B-fragments for this wave's 16-n tile (2 k-halves) ----
    const int nrow = wv * 16 + lr;
    const int swk = (lr & 7) << 4;
    bf16x8 bfr[2];
    #pragma unroll
    for (int kk = 0; kk < 2; ++kk) {
        const int roff = nrow * 128 + (((kk * 4 + lg) * 16) ^ swk);
        bfr[kk] = *reinterpret_cast<const bf16x8*>(NodeL + roff);
    }

    // ---- f-loop: transient A-fragments (W row o0+lr, L1-hot), 2 MFMA each ----
    f32x4 acc[FL];
    #pragma unroll
    for (int f = 0; f < FL; ++f) acc[f] = f32x4{0.f, 0.f, 0.f, 0.f};

    const float* wrow = W + (size_t)(o0 + lr) * (FL * WROW) + lg * 8;
    #pragma unroll
    for (int f = 0; f < FL; ++f) {
        const float* p = wrow + f * WROW;
        #pragma unroll
        for (int kk = 0; kk < 2; ++kk) {
            const f32x4a u0 = *reinterpret_cast<const f32x4a*>(p + kk * 32);
            const f32x4a u1 = *reinterpret_cast<const f32x4a*>(p + kk * 32 + 4);
            bf16x8 a;
            a[0] = (__bf16)u0.x; a[1] = (__bf16)u0.y;
            a[2] = (__bf16)u0.z; a[3] = (__bf16)u0.w;
            a[4] = (__bf16)u1.x; a[5] = (__bf16)u1.y;
            a[6] = (__bf16)u1.z; a[7] = (__bf16)u1.w;
            acc[f] = __builtin_amdgcn_mfma_f32_16x16x32_bf16(a, bfr[kk], acc[f], 0, 0, 0);
        }
    }

    // ---- direct store: lane r -> o = o0+4*lg+r, n = nbase+wv*16+lr ----
    #pragma unroll
    for (int r = 0; r < 4; ++r) {
        const int o = o0 + 4 * lg + r;
        const int n = nbase + wv * 16 + lr;
        union { __bf16 b[FL]; uint2 u[3]; } pk;
        #pragma unroll
        for (int f = 0; f < FL; ++f) pk.b[f] = (__bf16)acc[f][r];
        uint2* dst = reinterpret_cast<uint2*>(
            gt + ((size_t)(s * OD + o)) * KTOT + (size_t)n * FL);
        dst[0] = pk.u[0]; dst[1] = pk.u[1]; dst[2] = pk.u[2];
    }
}

// ---------------------------------------------------------------------------
// Kernel 2 (standalone again — fusion regressed): bond-term base for k_main.
// ---------------------------------------------------------------------------
__global__ __launch_bounds__(256)
void k_init(const float* __restrict__ bond, const float* __restrict__ W,
            float* __restrict__ out) {
    const int bid = blockIdx.x;
    const int tid = threadIdx.x;

    __shared__ float Wb[64][25];
    for (int i = tid; i < 64 * 24; i += 256) {
        const int o = i / 24, fc = i % 24;
        const int f = fc >> 1, c = fc & 1;
        Wb[o][fc] = W[(size_t)o * (FL * WROW) + f * WROW + IND + c];
    }
    __shared__ float bl[4][24];
    if (tid < 96) {
        const int a = tid / 24, fc = tid % 24;
        bl[a][fc] = bond[(size_t)bid * 4 * (FL * 2) + a * (FL * 2) + fc];
    }
    __syncthreads();

    const int aL = tid >> 6, o = tid & 63;
    float sum = 0.f;
    #pragma unroll
    for (int f = 0; f < FL; ++f)
        sum += bl[aL][2 * f] * Wb[o][2 * f] + bl[aL][2 * f + 1] * Wb[o][2 * f + 1];
    out[((size_t)bid * 4 + aL) * OD + o] = sum;
}

// ---------------------------------------------------------------------------
// Kernel 3 (validated ~86us, untouched): pipelined LDS-staged MFMA GEMM.
// One raw s_barrier per K-step, explicit lgkmcnt(0) (no vmcnt drain), 2-deep
// register prefetch -> counted vmcnt waits, loads in flight across barriers.
// ---------------------------------------------------------------------------
struct PF { f32x4 a0, a1, a2, a3; uint4 b0, b1; };

__device__ __forceinline__ PF pf_load(const float* ap, const __bf16* bp) {
    PF p;
    p.a0 = *reinterpret_cast<const f32x4*>(ap);
    p.a1 = *reinterpret_cast<const f32x4*>(ap + 4);
    p.a2 = *reinterpret_cast<const f32x4*>(ap + 8);
    p.a3 = *reinterpret_cast<const f32x4*>(ap + 12);
    p.b0 = *reinterpret_cast<const uint4*>(bp);
    p.b1 = *reinterpret_cast<const uint4*>(bp + 8);
    return p;
}

__device__ __forceinline__ void pf_stage(unsigned char* Ab, unsigned char* Bb,
                                         const PF& p, int woff0, int woff1) {
    bf16x8 wlo, whi;
    wlo[0] = (__bf16)p.a0.x; wlo[1] = (__bf16)p.a0.y;
    wlo[2] = (__bf16)p.a0.z; wlo[3] = (__bf16)p.a0.w;
    wlo[4] = (__bf16)p.a1.x; wlo[5] = (__bf16)p.a1.y;
    wlo[6] = (__bf16)p.a1.z; wlo[7] = (__bf16)p.a1.w;
    whi[0] = (__bf16)p.a2.x; whi[1] = (__bf16)p.a2.y;
    whi[2] = (__bf16)p.a2.z; whi[3] = (__bf16)p.a2.w;
    whi[4] = (__bf16)p.a3.x; whi[5] = (__bf16)p.a3.y;
    whi[6] = (__bf16)p.a3.z; whi[7] = (__bf16)p.a3.w;
    *reinterpret_cast<bf16x8*>(Ab + woff0) = wlo;
    *reinterpret_cast<bf16x8*>(Ab + woff1) = whi;
    *reinterpret_cast<uint4*>(Bb + woff0) = p.b0;
    *reinterpret_cast<uint4*>(Bb + woff1) = p.b1;
}

__device__ __forceinline__ void mfma_phase(const unsigned char* Ab, const unsigned char* Bb,
                                           int rowA0, int rowB0, int lg, int rsw,
                                           f32x4& c00, f32x4& c01, f32x4& c10, f32x4& c11) {
    #pragma unroll
    for (int ks = 0; ks < 2; ++ks) {
        const int koff = (ks * 64 + lg * 16) ^ rsw;
        const bf16x8 am0 = *reinterpret_cast<const bf16x8*>(Ab + rowA0 + koff);
        const bf16x8 am1 = *reinterpret_cast<const bf16x8*>(Ab + rowA0 + 2048 + koff);
        const bf16x8 bn0 = *reinterpret_cast<const bf16x8*>(Bb + rowB0 + koff);
        const bf16x8 bn1 = *reinterpret_cast<const bf16x8*>(Bb + rowB0 + 2048 + koff);
        c00 = __builtin_amdgcn_mfma_f32_16x16x32_bf16(am0, bn0, c00, 0, 0, 0);
        c01 = __builtin_amdgcn_mfma_f32_16x16x32_bf16(am0, bn1, c01, 0, 0, 0);
        c10 = __builtin_amdgcn_mfma_f32_16x16x32_bf16(am1, bn0, c10, 0, 0, 0);
        c11 = __builtin_amdgcn_mfma_f32_16x16x32_bf16(am1, bn1, c11, 0, 0, 0);
    }
}

__global__ __launch_bounds__(256, 4)
void k_main(const float* __restrict__ conn, const __bf16* __restrict__ gt,
            float* __restrict__ out) {
    const int bid = blockIdx.x;
    const int s  = bid & 31;
    const int x  = bid >> 5;
    const int at = x >> 2;            // 0..7
    const int kq = x & 3;             // 0..3
    const int a0 = at << 6;
    const int k00 = kq * (KTOT / 4);  // 1536-elem K slice, 24 steps of 64
    const int tid = threadIdx.x;
    const int w  = tid >> 6, l = tid & 63;
    const int lr = l & 15, lg = l >> 4;
    const int m0 = (w >> 1) << 5;
    const int n0 = (w & 1) << 5;

    __shared__ __align__(16) unsigned char Al0[8192];
    __shared__ __align__(16) unsigned char Al1[8192];
    __shared__ __align__(16) unsigned char Bl0[8192];
    __shared__ __align__(16) unsigned char Bl1[8192];

    const int srow = tid >> 2;
    const int scol = tid & 3;
    const float*  aG = conn + ((size_t)s * NA + a0 + srow) * KTOT + k00 + scol * 16;
    const __bf16* bG = gt   + ((size_t)s * OD + srow)      * KTOT + k00 + scol * 16;
    const int wsw   = (srow & 7) << 4;
    const int woff0 = srow * 128 + ((scol * 32) ^ wsw);
    const int woff1 = srow * 128 + ((scol * 32 + 16) ^ wsw);

    f32x4 acc00 = {0.f,0.f,0.f,0.f}, acc01 = {0.f,0.f,0.f,0.f};
    f32x4 acc10 = {0.f,0.f,0.f,0.f}, acc11 = {0.f,0.f,0.f,0.f};

    const int rsw = (lr & 7) << 4;
    const int rowA0 = (m0 + lr) * 128;
    const int rowB0 = (n0 + lr) * 128;

    PF P0 = pf_load(aG, bG);
    PF P1 = pf_load(aG + 64, bG + 64);

    #pragma unroll 1
    for (int t = 0; t < 24; t += 2) {
        // ---- even step: buffer 0 ----
        pf_stage(Al0, Bl0, P0, woff0, woff1);          // waits vmcnt(6): P1 in flight
        if (t + 2 < 24) P0 = pf_load(aG + (t + 2) * 64, bG + (t + 2) * 64);
        asm volatile("s_waitcnt lgkmcnt(0)" ::: "memory");
        __builtin_amdgcn_s_barrier();
        mfma_phase(Al0, Bl0, rowA0, rowB0, lg, rsw, acc00, acc01, acc10, acc11);

        // ---- odd step: buffer 1 ----
        pf_stage(Al1, Bl1, P1, woff0, woff1);
        if (t + 3 < 24) P1 = pf_load(aG + (t + 3) * 64, bG + (t + 3) * 64);
        asm volatile("s_waitcnt lgkmcnt(0)" ::: "memory");
        __builtin_amdgcn_s_barrier();
        mfma_phase(Al1, Bl1, rowA0, rowB0, lg, rsw, acc00, acc01, acc10, acc11);
    }

    // epilogue: atomic accumulate partials. D: col=lane&15, row=4*(lane>>4)+r
    float* ob = out + ((size_t)s * NA + a0 + m0 + lg * 4) * OD + n0 + lr;
    #pragma unroll
    for (int r = 0; r < 4; ++r) {
        atomicAdd(ob + (size_t)(r) * OD,            acc00[r]);
        atomicAdd(ob + (size_t)(r) * OD + 16,       acc01[r]);
        atomicAdd(ob + (size_t)(16 + r) * OD,       acc10[r]);
        atomicAdd(ob + (size_t)(16 + r) * OD + 16,  acc11[r]);
    }
}

extern "C" void kernel_launch(void* const* d_in, const int* in_sizes, int n_in,
                              void* d_out, int out_size, void* d_ws, size_t ws_size,
                              hipStream_t stream) {
    const float* node = (const float*)d_in[0];
    const float* conn = (const float*)d_in[1];
    const float* bond = (const float*)d_in[2];
    const float* W    = (const float*)d_in[3];
    float* out = (float*)d_out;
    __bf16* gt = (__bf16*)d_ws;    // 32*64*6144 bf16 = 25.2 MB

    k_prep<<<dim3(1024), dim3(256), 0, stream>>>(node, W, gt);
    k_init<<<dim3(NS * NA / 4), dim3(256), 0, stream>>>(bond, W, out);
    k_main<<<dim3(NS * 32), dim3(256), 0, stream>>>(conn, gt, out);
}